// Round 1
// baseline (111.555 us; speedup 1.0000x reference)
//
#include <hip/hip_runtime.h>

#define BATCH   32
#define SEQ     2048
#define MDIM    128
#define LBAS    64
#define NW      2041        // SEQ - RANK + 1
#define WTILE   64
#define APAD    136         // bf16 elems per LDS row: 16B-aligned, spreads bank quads

typedef __attribute__((ext_vector_type(8))) short  short8;
typedef __attribute__((ext_vector_type(4))) float  float4v;

// round-to-nearest-even fp32 -> bf16 (inputs finite; no NaN path needed)
__device__ __forceinline__ unsigned short f2bf(float f) {
    unsigned int u = __float_as_uint(f);
    unsigned int r = (u + 0x7FFFu + ((u >> 16) & 1u)) >> 16;
    return (unsigned short)r;
}

__global__ __launch_bounds__(256, 2)
void ndd_fused(const float* __restrict__ x,      // [32][2048][128]
               const float* __restrict__ Mmat,   // [128][128]
               const float* __restrict__ Acoeff, // [128][64]
               const float* __restrict__ Bbasis, // [64][128]
               float* __restrict__ out)
{
    __shared__ __align__(16) unsigned short sM[MDIM * APAD];   // bf16 M[n][m]
    __shared__ __align__(16) unsigned short sA[WTILE * APAD];  // bf16 agg[w][m]
    __shared__ float sred[4];

    const int tid = threadIdx.x;
    const int wt  = blockIdx.x;          // 0..31 window tile
    const int b   = blockIdx.y;          // 0..31 batch
    const int W0  = wt * WTILE;

    // ---------------- stage M as bf16 (layout = B-fragment-ready) ----------------
    {
        const float4v* M4 = reinterpret_cast<const float4v*>(Mmat);
        #pragma unroll
        for (int i = 0; i < 16; ++i) {
            int idx4 = i * 256 + tid;            // 0..4095 float4s
            int n    = idx4 >> 5;                // row
            int m4   = idx4 & 31;                // float4 col
            float4v v = M4[idx4];
            unsigned int lo = (unsigned)f2bf(v.x) | ((unsigned)f2bf(v.y) << 16);
            unsigned int hi = (unsigned)f2bf(v.z) | ((unsigned)f2bf(v.w) << 16);
            *reinterpret_cast<unsigned long long*>(&sM[n * APAD + m4 * 4]) =
                ((unsigned long long)hi << 32) | lo;
        }
    }

    // ---------------- stage agg[w][m] = mean of 8 rows, bf16 ----------------
    {
        const int m4   = tid & 31;               // float4 column 0..31
        const int wseg = tid >> 5;               // 0..7 -> 8 windows each
        const int w0   = wseg * 8;
        const float4v* xb = reinterpret_cast<const float4v*>(x) + (size_t)b * SEQ * 32;

        float4v rbuf[8];
        float4v acc = {0.f, 0.f, 0.f, 0.f};
        const bool seg_valid = (W0 + w0) < NW;
        #pragma unroll
        for (int r = 0; r < 8; ++r) {
            float4v v = {0.f, 0.f, 0.f, 0.f};
            if (seg_valid) v = xb[(W0 + w0 + r) * 32 + m4];   // row <= 2047 guaranteed
            rbuf[r] = v;
            acc += v;
        }
        {   // store w0
            unsigned int lo = 0u, hi = 0u;
            if (seg_valid) {
                lo = (unsigned)f2bf(acc.x * 0.125f) | ((unsigned)f2bf(acc.y * 0.125f) << 16);
                hi = (unsigned)f2bf(acc.z * 0.125f) | ((unsigned)f2bf(acc.w * 0.125f) << 16);
            }
            *reinterpret_cast<unsigned long long*>(&sA[w0 * APAD + m4 * 4]) =
                ((unsigned long long)hi << 32) | lo;
        }
        #pragma unroll
        for (int j = 1; j < 8; ++j) {
            int w = w0 + j;
            bool ok = (W0 + w) < NW;
            float4v vn = {0.f, 0.f, 0.f, 0.f};
            if (ok) vn = xb[(W0 + w + 7) * 32 + m4];          // row <= 2047 when ok
            acc = acc + vn - rbuf[j - 1];
            unsigned int lo = 0u, hi = 0u;
            if (ok) {
                lo = (unsigned)f2bf(acc.x * 0.125f) | ((unsigned)f2bf(acc.y * 0.125f) << 16);
                hi = (unsigned)f2bf(acc.z * 0.125f) | ((unsigned)f2bf(acc.w * 0.125f) << 16);
            }
            *reinterpret_cast<unsigned long long*>(&sA[w * APAD + m4 * 4]) =
                ((unsigned long long)hi << 32) | lo;
        }
    }

    __syncthreads();

    // ---------------- MFMA GEMM: C[w][n] = sum_m agg[w][m] * M[n][m] ----------------
    const int lane = tid & 63;
    const int wave = tid >> 6;       // 0..3, each owns 32 n-columns
    const int l15  = lane & 15;
    const int q    = lane >> 4;      // 0..3
    const int nb   = wave * 32;

    float4v accf[4][2];
    #pragma unroll
    for (int wi = 0; wi < 4; ++wi)
        #pragma unroll
        for (int nj = 0; nj < 2; ++nj)
            accf[wi][nj] = (float4v){0.f, 0.f, 0.f, 0.f};

    #pragma unroll
    for (int kk = 0; kk < 4; ++kk) {
        const int koff = kk * 32 + q * 8;
        short8 af[4], bf[2];
        #pragma unroll
        for (int wi = 0; wi < 4; ++wi)
            af[wi] = *reinterpret_cast<const short8*>(&sA[(wi * 16 + l15) * APAD + koff]);
        #pragma unroll
        for (int nj = 0; nj < 2; ++nj)
            bf[nj] = *reinterpret_cast<const short8*>(&sM[(nb + nj * 16 + l15) * APAD + koff]);
        #pragma unroll
        for (int wi = 0; wi < 4; ++wi)
            #pragma unroll
            for (int nj = 0; nj < 2; ++nj)
                accf[wi][nj] = __builtin_amdgcn_mfma_f32_16x16x32_bf16(
                    af[wi], bf[nj], accf[wi][nj], 0, 0, 0);
    }

    // ---------------- epilogue: (C - Nk)^2, masked, reduce ----------------
    // k = (W0 + w) % 64 == w  because W0 is a multiple of 64 and w < 64.
    float local = 0.f;
    #pragma unroll
    for (int wi = 0; wi < 4; ++wi) {
        #pragma unroll
        for (int nj = 0; nj < 2; ++nj) {
            const int n = nb + nj * 16 + l15;
            #pragma unroll
            for (int r = 0; r < 4; ++r) {
                const int w = wi * 16 + q * 4 + r;     // C/D: row=(lane>>4)*4+reg
                if (W0 + w < NW) {
                    const float nk = Acoeff[n * LBAS + w] * Bbasis[w * MDIM + n];
                    const float d  = accf[wi][nj][r] - nk;
                    local += d * d;
                }
            }
        }
    }

    #pragma unroll
    for (int off = 32; off > 0; off >>= 1)
        local += __shfl_down(local, off, 64);
    if (lane == 0) sred[wave] = local;
    __syncthreads();
    if (tid == 0) {
        float t = (sred[0] + sred[1]) + (sred[2] + sred[3]);
        atomicAdd(out, t * (1.0f / 8359936.0f));   // 1/(32*2041*128)
    }
}

extern "C" void kernel_launch(void* const* d_in, const int* in_sizes, int n_in,
                              void* d_out, int out_size, void* d_ws, size_t ws_size,
                              hipStream_t stream) {
    const float* x      = (const float*)d_in[0];
    const float* Mmat   = (const float*)d_in[1];
    const float* Acoef  = (const float*)d_in[2];
    const float* Bbas   = (const float*)d_in[3];
    float* out          = (float*)d_out;

    hipMemsetAsync(out, 0, sizeof(float), stream);
    dim3 grid(32, BATCH);   // 32 w-tiles x 32 batches = 1024 blocks
    ndd_fused<<<grid, 256, 0, stream>>>(x, Mmat, Acoef, Bbas, out);
}

// Round 2
// 110.481 us; speedup vs baseline: 1.0097x; 1.0097x over previous
//
#include <hip/hip_runtime.h>

#define BATCH   32
#define SEQ     2048
#define MDIM    128
#define LBAS    64
#define NW      2041        // SEQ - RANK + 1
#define WTILE   32
#define APAD    136         // bf16 elems per LDS row: 16B-aligned, spreads bank quads

typedef __attribute__((ext_vector_type(8))) short  short8;
typedef __attribute__((ext_vector_type(4))) float  float4v;

// round-to-nearest-even fp32 -> bf16
__device__ __forceinline__ unsigned short f2bf(float f) {
    unsigned int u = __float_as_uint(f);
    unsigned int r = (u + 0x7FFFu + ((u >> 16) & 1u)) >> 16;
    return (unsigned short)r;
}

// ---------------------------------------------------------------------------
// Prep: (a) M fp32[128][128] -> bf16 in B-fragment-linear layout
//           Mb[(k>>3)][n][j] , k-chunk plane p = k/8 (16 planes of 128x8)
//       (b) nk[k][n] = Acoeff[n][k] * Bbasis[k][n]  (fp32, 64x128)
// ---------------------------------------------------------------------------
__global__ __launch_bounds__(256)
void ndd_prep(const float* __restrict__ Mmat,
              const float* __restrict__ Acoeff,
              const float* __restrict__ Bbasis,
              unsigned short* __restrict__ Mb,
              float* __restrict__ nk)
{
    const int gid = blockIdx.x * 256 + threadIdx.x;
    if (gid < 2048) {                    // 128 rows x 16 chunks
        const int n = gid >> 4;
        const int c = gid & 15;
        const float* src = Mmat + n * MDIM + c * 8;
        short8 v;
        #pragma unroll
        for (int j = 0; j < 8; ++j) v[j] = (short)f2bf(src[j]);
        *reinterpret_cast<short8*>(Mb + ((size_t)(c * MDIM + n)) * 8) = v;
    } else if (gid < 2048 + 8192) {      // 64 x 128 nk table
        const int e = gid - 2048;
        const int k = e >> 7;
        const int n = e & 127;
        nk[k * MDIM + n] = Acoeff[n * LBAS + k] * Bbasis[k * MDIM + n];
    }
}

// ---------------------------------------------------------------------------
// Main: per block = 32 windows x 1 batch. agg staged bf16 in LDS; B fragments
// read directly from L2-resident Mb; (C-nk)^2 reduced to one atomicAdd.
// ---------------------------------------------------------------------------
__global__ __launch_bounds__(256, 6)
void ndd_main(const float* __restrict__ x,            // [32][2048][128]
              const unsigned short* __restrict__ Mb,  // bf16, frag-linear
              const float* __restrict__ nk,           // [64][128]
              float* __restrict__ out)
{
    __shared__ __align__(16) unsigned short sA[WTILE * APAD];
    __shared__ float sred[4];

    const int tid = threadIdx.x;
    const int W0  = blockIdx.x * WTILE;   // 0..2016
    const int b   = blockIdx.y;

    // ---- stage agg[w][m] = mean of 8 rows, bf16 (running sum, 4 windows/thr) ----
    {
        const int m4  = tid & 31;         // float4 column
        const int seg = tid >> 5;         // 0..7
        const int w0  = seg * 4;
        const float4v* xb = reinterpret_cast<const float4v*>(x) + (size_t)b * SEQ * 32;

        float4v rbuf[3];
        float4v acc = {0.f, 0.f, 0.f, 0.f};
        const bool sv = (W0 + w0) < NW;
        #pragma unroll
        for (int r = 0; r < 8; ++r) {
            float4v v = {0.f, 0.f, 0.f, 0.f};
            if (sv) v = xb[(W0 + w0 + r) * 32 + m4];   // rows <= 2047 when valid
            if (r < 3) rbuf[r] = v;
            acc += v;
        }
        {
            unsigned int lo = 0u, hi = 0u;
            if (sv) {
                lo = (unsigned)f2bf(acc.x * 0.125f) | ((unsigned)f2bf(acc.y * 0.125f) << 16);
                hi = (unsigned)f2bf(acc.z * 0.125f) | ((unsigned)f2bf(acc.w * 0.125f) << 16);
            }
            *reinterpret_cast<unsigned long long*>(&sA[w0 * APAD + m4 * 4]) =
                ((unsigned long long)hi << 32) | lo;
        }
        #pragma unroll
        for (int j = 1; j < 4; ++j) {
            const bool ok = (W0 + w0 + j) < NW;
            float4v vn = {0.f, 0.f, 0.f, 0.f};
            if (ok) vn = xb[(W0 + w0 + j + 7) * 32 + m4];
            acc = acc + vn - rbuf[j - 1];
            unsigned int lo = 0u, hi = 0u;
            if (ok) {
                lo = (unsigned)f2bf(acc.x * 0.125f) | ((unsigned)f2bf(acc.y * 0.125f) << 16);
                hi = (unsigned)f2bf(acc.z * 0.125f) | ((unsigned)f2bf(acc.w * 0.125f) << 16);
            }
            *reinterpret_cast<unsigned long long*>(&sA[(w0 + j) * APAD + m4 * 4]) =
                ((unsigned long long)hi << 32) | lo;
        }
    }

    __syncthreads();

    // ---- MFMA: C[w][n] = sum_m agg[w][m] * M[n][m], B frags from global ----
    const int lane = tid & 63;
    const int wave = tid >> 6;        // 0..3, owns 32 n-cols
    const int l15  = lane & 15;
    const int q    = lane >> 4;       // 0..3
    const int nb   = wave * 32;

    float4v accf[2][2];
    #pragma unroll
    for (int wi = 0; wi < 2; ++wi)
        #pragma unroll
        for (int nj = 0; nj < 2; ++nj)
            accf[wi][nj] = (float4v){0.f, 0.f, 0.f, 0.f};

    #pragma unroll
    for (int kk = 0; kk < 4; ++kk) {
        const int koff = kk * 32 + q * 8;
        short8 af[2], bf[2];
        #pragma unroll
        for (int wi = 0; wi < 2; ++wi)
            af[wi] = *reinterpret_cast<const short8*>(&sA[(wi * 16 + l15) * APAD + koff]);
        #pragma unroll
        for (int nj = 0; nj < 2; ++nj)
            bf[nj] = *reinterpret_cast<const short8*>(
                Mb + ((size_t)((kk * 4 + q) * MDIM + nb + nj * 16 + l15)) * 8);
        #pragma unroll
        for (int wi = 0; wi < 2; ++wi)
            #pragma unroll
            for (int nj = 0; nj < 2; ++nj)
                accf[wi][nj] = __builtin_amdgcn_mfma_f32_16x16x32_bf16(
                    af[wi], bf[nj], accf[wi][nj], 0, 0, 0);
    }

    // ---- epilogue: (C - nk)^2, masked, block reduce, one atomic ----
    float local = 0.f;
    #pragma unroll
    for (int wi = 0; wi < 2; ++wi) {
        #pragma unroll
        for (int nj = 0; nj < 2; ++nj) {
            const int n = nb + nj * 16 + l15;
            #pragma unroll
            for (int r = 0; r < 4; ++r) {
                const int w = wi * 16 + q * 4 + r;       // C/D row map
                if (W0 + w < NW) {
                    const float v = nk[((W0 + w) & 63) * MDIM + n];
                    const float d = accf[wi][nj][r] - v;
                    local += d * d;
                }
            }
        }
    }

    #pragma unroll
    for (int off = 32; off > 0; off >>= 1)
        local += __shfl_down(local, off, 64);
    if (lane == 0) sred[wave] = local;
    __syncthreads();
    if (tid == 0) {
        float t = (sred[0] + sred[1]) + (sred[2] + sred[3]);
        atomicAdd(out, t * (1.0f / 8359936.0f));   // 1/(32*2041*128)
    }
}

extern "C" void kernel_launch(void* const* d_in, const int* in_sizes, int n_in,
                              void* d_out, int out_size, void* d_ws, size_t ws_size,
                              hipStream_t stream) {
    const float* x     = (const float*)d_in[0];
    const float* Mmat  = (const float*)d_in[1];
    const float* Acoef = (const float*)d_in[2];
    const float* Bbas  = (const float*)d_in[3];
    float* out         = (float*)d_out;

    unsigned short* Mb = (unsigned short*)d_ws;                 // 32 KB bf16
    float* nkp         = (float*)((char*)d_ws + 32768);         // 32 KB fp32

    hipMemsetAsync(out, 0, sizeof(float), stream);
    ndd_prep<<<40, 256, 0, stream>>>(Mmat, Acoef, Bbas, Mb, nkp);
    dim3 grid(64, BATCH);    // 64 w-tiles x 32 batches = 2048 blocks
    ndd_main<<<grid, 256, 0, stream>>>(x, Mb, nkp, out);
}

// Round 3
// 89.527 us; speedup vs baseline: 1.2460x; 1.2340x over previous
//
#include <hip/hip_runtime.h>

#define BATCH   32
#define SEQ     2048
#define MDIM    128
#define LBAS    64
#define NW      2041        // SEQ - RANK + 1
#define WTILE   32
#define NROWS   40          // raw rows staged per tile (39 needed, padded)
#define APAD    136

typedef __attribute__((ext_vector_type(8))) short  short8;
typedef __attribute__((ext_vector_type(4))) float  float4v;

__device__ __forceinline__ unsigned short f2bf(float f) {
    unsigned int u = __float_as_uint(f);
    return (unsigned short)((u + 0x7FFFu + ((u >> 16) & 1u)) >> 16);
}

// ---------------------------------------------------------------------------
// Prep: M -> bf16 B-fragment-linear; nk[k][n] = Acoeff[n][k]*Bbasis[k][n]
// ---------------------------------------------------------------------------
__global__ __launch_bounds__(256)
void ndd_prep(const float* __restrict__ Mmat,
              const float* __restrict__ Acoeff,
              const float* __restrict__ Bbasis,
              unsigned short* __restrict__ Mb,
              float* __restrict__ nk)
{
    const int gid = blockIdx.x * 256 + threadIdx.x;
    if (gid < 2048) {                    // 128 rows x 16 k-chunks
        const int n = gid >> 4;
        const int c = gid & 15;
        const float* src = Mmat + n * MDIM + c * 8;
        short8 v;
        #pragma unroll
        for (int j = 0; j < 8; ++j) v[j] = (short)f2bf(src[j]);
        *reinterpret_cast<short8*>(Mb + ((size_t)(c * MDIM + n)) * 8) = v;
    } else if (gid < 2048 + 8192) {      // 64 x 128 nk table
        const int e = gid - 2048;
        const int k = e >> 7;
        const int n = e & 127;
        nk[k * MDIM + n] = Acoeff[n * LBAS + k] * Bbasis[k * MDIM + n];
    }
}

// ---------------------------------------------------------------------------
// Main: async-stage raw x rows into LDS (global_load_lds, no VGPR roundtrip),
// window means from LDS, MFMA GEMM vs L2-resident Mb, masked MSE partial.
// ---------------------------------------------------------------------------
__global__ __launch_bounds__(256, 5)
void ndd_main(const float* __restrict__ x,            // [32][2048][128]
              const unsigned short* __restrict__ Mb,  // bf16 frag-linear
              const float* __restrict__ nk,           // [64][128]
              float* __restrict__ partial)            // [2048]
{
    __shared__ __align__(16) float sRaw[NROWS * MDIM];          // 20.5 KB raw fp32
    __shared__ __align__(16) unsigned short sA[WTILE * APAD];   // 8.7 KB bf16 agg
    __shared__ float sred[4];

    const int tid  = threadIdx.x;
    const int lane = tid & 63;
    const int wave = tid >> 6;
    const int W0   = blockIdx.x * WTILE;   // 0..2016
    const int b    = blockIdx.y;

    // ---- phase 1: 20 async 1KB chunks (2 rows each), 5 per wave ----
    {
        const float* xb = x + ((size_t)b * SEQ + W0) * MDIM;
        #pragma unroll
        for (int i = 0; i < 5; ++i) {
            const int c = wave * 5 + i;                 // chunk id 0..19
            if (W0 + 2 * c + 1 < SEQ) {                 // wave-uniform guard
                const float* g = xb + c * 256 + lane * 4;
                __builtin_amdgcn_global_load_lds(
                    (const __attribute__((address_space(1))) void*)g,
                    (__attribute__((address_space(3))) void*)&sRaw[c * 256],
                    16, 0, 0);
            }
        }
    }
    __syncthreads();

    // ---- phase 2: window means from LDS, bf16 into sA (unconditional) ----
    {
        const int m4 = tid & 31;            // float4 column
        const int w0 = (tid >> 5) * 4;      // 4 windows per thread
        const float4v* R = reinterpret_cast<const float4v*>(sRaw);
        float4v acc = {0.f, 0.f, 0.f, 0.f};
        #pragma unroll
        for (int r = 0; r < 8; ++r) acc += R[(w0 + r) * 32 + m4];
        #pragma unroll
        for (int j = 0; j < 4; ++j) {
            if (j) acc += R[(w0 + j + 7) * 32 + m4] - R[(w0 + j - 1) * 32 + m4];
            unsigned int lo = (unsigned)f2bf(acc.x * 0.125f) | ((unsigned)f2bf(acc.y * 0.125f) << 16);
            unsigned int hi = (unsigned)f2bf(acc.z * 0.125f) | ((unsigned)f2bf(acc.w * 0.125f) << 16);
            *reinterpret_cast<unsigned long long*>(&sA[(w0 + j) * APAD + m4 * 4]) =
                ((unsigned long long)hi << 32) | lo;
        }
    }
    __syncthreads();

    // ---- phase 3: MFMA C[w][n] = sum_m agg[w][m] * M[n][m] ----
    const int l15 = lane & 15;
    const int q   = lane >> 4;
    const int nb  = wave * 32;

    float4v accf[2][2];
    #pragma unroll
    for (int wi = 0; wi < 2; ++wi)
        #pragma unroll
        for (int nj = 0; nj < 2; ++nj)
            accf[wi][nj] = (float4v){0.f, 0.f, 0.f, 0.f};

    #pragma unroll
    for (int kk = 0; kk < 4; ++kk) {
        const int koff = kk * 32 + q * 8;
        short8 af[2], bfr[2];
        #pragma unroll
        for (int wi = 0; wi < 2; ++wi)
            af[wi] = *reinterpret_cast<const short8*>(&sA[(wi * 16 + l15) * APAD + koff]);
        #pragma unroll
        for (int nj = 0; nj < 2; ++nj)
            bfr[nj] = *reinterpret_cast<const short8*>(
                Mb + ((size_t)((kk * 4 + q) * MDIM + nb + nj * 16 + l15)) * 8);
        #pragma unroll
        for (int wi = 0; wi < 2; ++wi)
            #pragma unroll
            for (int nj = 0; nj < 2; ++nj)
                accf[wi][nj] = __builtin_amdgcn_mfma_f32_16x16x32_bf16(
                    af[wi], bfr[nj], accf[wi][nj], 0, 0, 0);
    }

    // ---- epilogue: (C - nk)^2 masked, block partial (no atomics) ----
    float local = 0.f;
    #pragma unroll
    for (int wi = 0; wi < 2; ++wi) {
        #pragma unroll
        for (int nj = 0; nj < 2; ++nj) {
            const int n = nb + nj * 16 + l15;
            #pragma unroll
            for (int r = 0; r < 4; ++r) {
                const int w = wi * 16 + q * 4 + r;     // C/D row map
                if (W0 + w < NW) {
                    const float v = nk[((W0 + w) & 63) * MDIM + n];
                    const float d = accf[wi][nj][r] - v;
                    local += d * d;
                }
            }
        }
    }
    #pragma unroll
    for (int off = 32; off > 0; off >>= 1)
        local += __shfl_down(local, off, 64);
    if (lane == 0) sred[wave] = local;
    __syncthreads();
    if (tid == 0)
        partial[blockIdx.y * 64 + blockIdx.x] =
            (sred[0] + sred[1]) + (sred[2] + sred[3]);
}

// ---------------------------------------------------------------------------
// Final reduce: 2048 partials -> scalar D
// ---------------------------------------------------------------------------
__global__ __launch_bounds__(256)
void ndd_reduce(const float* __restrict__ partial, float* __restrict__ out)
{
    __shared__ float sred[4];
    float s = 0.f;
    #pragma unroll
    for (int i = 0; i < 8; ++i) s += partial[i * 256 + threadIdx.x];
    #pragma unroll
    for (int off = 32; off > 0; off >>= 1) s += __shfl_down(s, off, 64);
    if ((threadIdx.x & 63) == 0) sred[threadIdx.x >> 6] = s;
    __syncthreads();
    if (threadIdx.x == 0)
        out[0] = ((sred[0] + sred[1]) + (sred[2] + sred[3])) * (1.0f / 8359936.0f);
}

extern "C" void kernel_launch(void* const* d_in, const int* in_sizes, int n_in,
                              void* d_out, int out_size, void* d_ws, size_t ws_size,
                              hipStream_t stream) {
    const float* x     = (const float*)d_in[0];
    const float* Mmat  = (const float*)d_in[1];
    const float* Acoef = (const float*)d_in[2];
    const float* Bbas  = (const float*)d_in[3];
    float* out         = (float*)d_out;

    unsigned short* Mb = (unsigned short*)d_ws;                 // 32 KB bf16
    float* nkp         = (float*)((char*)d_ws + 32768);         // 32 KB fp32
    float* part        = (float*)((char*)d_ws + 65536);         // 8 KB partials

    ndd_prep<<<40, 256, 0, stream>>>(Mmat, Acoef, Bbas, Mb, nkp);
    dim3 grid(64, BATCH);   // 2048 blocks
    ndd_main<<<grid, 256, 0, stream>>>(x, Mb, nkp, part);
    ndd_reduce<<<1, 256, 0, stream>>>(part, out);
}

// Round 4
// 85.697 us; speedup vs baseline: 1.3017x; 1.0447x over previous
//
#include <hip/hip_runtime.h>

#define BATCH   32
#define SEQ     2048
#define MDIM    128
#define LBAS    64
#define NW      2041        // SEQ - RANK + 1
#define WTILE   32
#define NROWS   40          // raw rows per tile buffer (39 needed, padded)
#define NT      4           // tiles per persistent block
#define APAD    136

typedef __attribute__((ext_vector_type(8))) short  short8;
typedef __attribute__((ext_vector_type(4))) float  float4v;

__device__ __forceinline__ unsigned short f2bf(float f) {
    unsigned int u = __float_as_uint(f);
    return (unsigned short)((u + 0x7FFFu + ((u >> 16) & 1u)) >> 16);
}

// ---------------------------------------------------------------------------
// Prep: M -> bf16 B-fragment-linear; nk[k][n] = Acoeff[n][k]*Bbasis[k][n]
// ---------------------------------------------------------------------------
__global__ __launch_bounds__(256)
void ndd_prep(const float* __restrict__ Mmat,
              const float* __restrict__ Acoeff,
              const float* __restrict__ Bbasis,
              unsigned short* __restrict__ Mb,
              float* __restrict__ nk)
{
    const int gid = blockIdx.x * 256 + threadIdx.x;
    if (gid < 2048) {                    // 128 rows x 16 k-chunks
        const int n = gid >> 4;
        const int c = gid & 15;
        const float* src = Mmat + n * MDIM + c * 8;
        short8 v;
        #pragma unroll
        for (int j = 0; j < 8; ++j) v[j] = (short)f2bf(src[j]);
        *reinterpret_cast<short8*>(Mb + ((size_t)(c * MDIM + n)) * 8) = v;
    } else if (gid < 2048 + 8192) {      // 64 x 128 nk table
        const int e = gid - 2048;
        const int k = e >> 7;
        const int n = e & 127;
        nk[k * MDIM + n] = Acoeff[n * LBAS + k] * Bbasis[k * MDIM + n];
    }
}

// ---------------------------------------------------------------------------
// Main: persistent blocks, 4 consecutive w-tiles each, double-buffered raw
// staging via global_load_lds; loads for tile j+1 fly during phase3 of j.
// ---------------------------------------------------------------------------
__global__ __launch_bounds__(256, 3)
void ndd_main(const float* __restrict__ x,            // [32][2048][128]
              const unsigned short* __restrict__ Mb,  // bf16 frag-linear
              const float* __restrict__ nk,           // [64][128]
              float* __restrict__ partial)            // [512]
{
    __shared__ __align__(16) float sRaw[2][NROWS * MDIM];       // 2 x 20 KB
    __shared__ __align__(16) unsigned short sA[WTILE * APAD];   // 8.7 KB
    __shared__ float sred[4];

    const int tid  = threadIdx.x;
    const int lane = tid & 63;
    const int wave = tid >> 6;
    const int b    = blockIdx.x >> 4;          // batch 0..31
    const int wtg  = blockIdx.x & 15;          // tile group: w-tiles wtg*4..+3
    const int l15  = lane & 15;
    const int q    = lane >> 4;
    const int nb   = wave * 32;

    const float* xb = x + (size_t)b * SEQ * MDIM;

    // ---- issue loads for tile 0 ----
    {
        const int W0 = (wtg * NT) * WTILE;
        #pragma unroll
        for (int i = 0; i < 5; ++i) {
            const int c = wave * 5 + i;
            if (2 * c + 1 <= 2047 - W0) {
                const float* g = xb + (size_t)(W0 + 2 * c) * MDIM + lane * 4;
                __builtin_amdgcn_global_load_lds(
                    (const __attribute__((address_space(1))) void*)g,
                    (__attribute__((address_space(3))) void*)&sRaw[0][c * 256],
                    16, 0, 0);
            }
        }
    }

    // ---- preload nk into registers: 2 parities x (wi,nj,r) = 32 floats ----
    float nkreg[2][2][2][4];
    #pragma unroll
    for (int p = 0; p < 2; ++p)
        #pragma unroll
        for (int wi = 0; wi < 2; ++wi)
            #pragma unroll
            for (int nj = 0; nj < 2; ++nj)
                #pragma unroll
                for (int r = 0; r < 4; ++r)
                    nkreg[p][wi][nj][r] =
                        nk[(p * 32 + wi * 16 + q * 4 + r) * MDIM + nb + nj * 16 + l15];

    float local = 0.f;

    for (int j = 0; j < NT; ++j) {
        const int W0 = (wtg * NT + j) * WTILE;
        const float4v* R = reinterpret_cast<const float4v*>(&sRaw[j & 1][0]);

        __syncthreads();   // drains loads(j)

        // ---- phase 2: window means -> bf16 sA ----
        {
            const int m4 = tid & 31;
            const int w0 = (tid >> 5) * 4;
            float4v acc = {0.f, 0.f, 0.f, 0.f};
            #pragma unroll
            for (int r = 0; r < 8; ++r) acc += R[(w0 + r) * 32 + m4];
            #pragma unroll
            for (int t = 0; t < 4; ++t) {
                if (t) acc += R[(w0 + t + 7) * 32 + m4] - R[(w0 + t - 1) * 32 + m4];
                unsigned int lo = (unsigned)f2bf(acc.x * 0.125f) | ((unsigned)f2bf(acc.y * 0.125f) << 16);
                unsigned int hi = (unsigned)f2bf(acc.z * 0.125f) | ((unsigned)f2bf(acc.w * 0.125f) << 16);
                *reinterpret_cast<unsigned long long*>(&sA[(w0 + t) * APAD + m4 * 4]) =
                    ((unsigned long long)hi << 32) | lo;
            }
        }

        __syncthreads();   // sA visible; vmcnt already 0 -> cheap

        // ---- issue loads for tile j+1 (fly during phase 3) ----
        if (j + 1 < NT) {
            const int W1 = (wtg * NT + j + 1) * WTILE;
            #pragma unroll
            for (int i = 0; i < 5; ++i) {
                const int c = wave * 5 + i;
                if (2 * c + 1 <= 2047 - W1) {
                    const float* g = xb + (size_t)(W1 + 2 * c) * MDIM + lane * 4;
                    __builtin_amdgcn_global_load_lds(
                        (const __attribute__((address_space(1))) void*)g,
                        (__attribute__((address_space(3))) void*)&sRaw[(j + 1) & 1][c * 256],
                        16, 0, 0);
                }
            }
        }

        // ---- phase 3: MFMA C[w][n] = sum_m agg[w][m] * M[n][m] ----
        float4v accf[2][2];
        #pragma unroll
        for (int wi = 0; wi < 2; ++wi)
            #pragma unroll
            for (int nj = 0; nj < 2; ++nj)
                accf[wi][nj] = (float4v){0.f, 0.f, 0.f, 0.f};

        #pragma unroll
        for (int kk = 0; kk < 4; ++kk) {
            const int koff = kk * 32 + q * 8;
            short8 af[2], bfr[2];
            #pragma unroll
            for (int wi = 0; wi < 2; ++wi)
                af[wi] = *reinterpret_cast<const short8*>(&sA[(wi * 16 + l15) * APAD + koff]);
            #pragma unroll
            for (int nj = 0; nj < 2; ++nj)
                bfr[nj] = *reinterpret_cast<const short8*>(
                    Mb + ((size_t)((kk * 4 + q) * MDIM + nb + nj * 16 + l15)) * 8);
            #pragma unroll
            for (int wi = 0; wi < 2; ++wi)
                #pragma unroll
                for (int nj = 0; nj < 2; ++nj)
                    accf[wi][nj] = __builtin_amdgcn_mfma_f32_16x16x32_bf16(
                        af[wi], bfr[nj], accf[wi][nj], 0, 0, 0);
        }

        // ---- epilogue: (C - nk)^2, masked, accumulate ----
        const int p = j & 1;
        #pragma unroll
        for (int wi = 0; wi < 2; ++wi) {
            #pragma unroll
            for (int nj = 0; nj < 2; ++nj) {
                #pragma unroll
                for (int r = 0; r < 4; ++r) {
                    const int w = wi * 16 + q * 4 + r;
                    if (W0 + w < NW) {
                        const float d = accf[wi][nj][r] - nkreg[p][wi][nj][r];
                        local += d * d;
                    }
                }
            }
        }
    }

    // ---- block reduce, one partial per block ----
    #pragma unroll
    for (int off = 32; off > 0; off >>= 1)
        local += __shfl_down(local, off, 64);
    if (lane == 0) sred[wave] = local;
    __syncthreads();
    if (tid == 0)
        partial[blockIdx.x] = (sred[0] + sred[1]) + (sred[2] + sred[3]);
}

// ---------------------------------------------------------------------------
// Final reduce: 512 partials -> scalar D
// ---------------------------------------------------------------------------
__global__ __launch_bounds__(256)
void ndd_reduce(const float* __restrict__ partial, float* __restrict__ out)
{
    __shared__ float sred[4];
    float s = partial[threadIdx.x] + partial[threadIdx.x + 256];
    #pragma unroll
    for (int off = 32; off > 0; off >>= 1) s += __shfl_down(s, off, 64);
    if ((threadIdx.x & 63) == 0) sred[threadIdx.x >> 6] = s;
    __syncthreads();
    if (threadIdx.x == 0)
        out[0] = ((sred[0] + sred[1]) + (sred[2] + sred[3])) * (1.0f / 8359936.0f);
}

extern "C" void kernel_launch(void* const* d_in, const int* in_sizes, int n_in,
                              void* d_out, int out_size, void* d_ws, size_t ws_size,
                              hipStream_t stream) {
    const float* x     = (const float*)d_in[0];
    const float* Mmat  = (const float*)d_in[1];
    const float* Acoef = (const float*)d_in[2];
    const float* Bbas  = (const float*)d_in[3];
    float* out         = (float*)d_out;

    unsigned short* Mb = (unsigned short*)d_ws;                 // 32 KB bf16
    float* nkp         = (float*)((char*)d_ws + 32768);         // 32 KB fp32
    float* part        = (float*)((char*)d_ws + 65536);         // 2 KB partials

    ndd_prep<<<40, 256, 0, stream>>>(Mmat, Acoef, Bbas, Mb, nkp);
    ndd_main<<<512, 256, 0, stream>>>(x, Mb, nkp, part);
    ndd_reduce<<<1, 256, 0, stream>>>(part, out);
}